// Round 6
// baseline (813.381 us; speedup 1.0000x reference)
//
#include <hip/hip_runtime.h>

#define HH 1024
#define WW 1024
#define RAD 8
#define EPSF 1e-4f
#define HWSZ (HH * WW)
#define NPLB 16  // ws planes per batch (boxed a/b only)
#define T2 216   // output cols per wave in k_stats_solve
#define NTL 5    // tiles per row (216*5 = 1080 >= 1024)
#define V3R 8    // rows per block, k_vbox_comb

// Inclusive wave64 prefix scan via DPP (VALU-only, no LDS pipe).
__device__ __forceinline__ float wave_incl_scan(float v) {
  int t;
  t = __builtin_amdgcn_update_dpp(0, __float_as_int(v), 0x111, 0xf, 0xf, false);
  v += __int_as_float(t);
  t = __builtin_amdgcn_update_dpp(0, __float_as_int(v), 0x112, 0xf, 0xf, false);
  v += __int_as_float(t);
  t = __builtin_amdgcn_update_dpp(0, __float_as_int(v), 0x114, 0xf, 0xf, false);
  v += __int_as_float(t);
  t = __builtin_amdgcn_update_dpp(0, __float_as_int(v), 0x118, 0xf, 0xf, false);
  v += __int_as_float(t);
  t = __builtin_amdgcn_update_dpp(0, __float_as_int(v), 0x142, 0xa, 0xf, false);
  v += __int_as_float(t);
  t = __builtin_amdgcn_update_dpp(0, __float_as_int(v), 0x143, 0xc, 0xf, false);
  v += __int_as_float(t);
  return v;
}

// ---------------- K_A: fused vbox(25 products on-the-fly from raw inputs)
// + hbox(25) + 3x3 solve + hbox(a/b) -> 16 boxed-a/b planes.
// One wave per (row, tile): covers cols [E, E+256), E = F-20; stores
// hboxed a/b at cols [F, F+216). Vertical box = 17-tap sum over raw rows
// (re-reads are L2/L3 hits); horizontal boxes via prefix-difference DPP scan.
__global__ __launch_bounds__(256) void k_stats_solve(const float* __restrict__ x,
                                                     const float* __restrict__ g,
                                                     float* __restrict__ ws, int b0) {
  const int lane = threadIdx.x & 63;
  const int w = threadIdx.x >> 6;
  const int bi = blockIdx.y;
  const int gw = blockIdx.x * 4 + w;  // 0 .. HH*NTL-1
  const int row = gw / NTL;
  const int tix = gw - row * NTL;
  const int b = b0 + bi;
  float* wsb = ws + (size_t)bi * NPLB * HWSZ;
  const int F = tix * T2;
  const int E = F - 20;
  const int relmax = (WW - 1) - E;
  const int col0 = E + 4 * lane;
  const bool ldok = (col0 >= 0) && (col0 < WW);

  const float* gp0 = g + (size_t)(b * 3 + 0) * HWSZ;
  const float* gp1 = g + (size_t)(b * 3 + 1) * HWSZ;
  const float* gp2 = g + (size_t)(b * 3 + 2) * HWSZ;
  const float* sp0 = x + (size_t)(b * 4 + 0) * HWSZ;
  const float* sp1 = x + (size_t)(b * 4 + 1) * HWSZ;
  const float* sp2 = x + (size_t)(b * 4 + 2) * HWSZ;
  const float* sp3 = x + (size_t)(b * 4 + 3) * HWSZ;

  // vertical 17-tap box of the 25 product channels, 4 cols/thread
  float s[25][4];
#pragma unroll
  for (int i = 0; i < 25; ++i) {
    s[i][0] = 0.f; s[i][1] = 0.f; s[i][2] = 0.f; s[i][3] = 0.f;
  }
  const float4 Z4 = make_float4(0.f, 0.f, 0.f, 0.f);
  for (int yy = row - RAD; yy <= row + RAD; ++yy) {
    if (yy < 0 || yy >= HH) continue;
    const int off = yy * WW + col0;
    const float4 G0 = ldok ? *(const float4*)(gp0 + off) : Z4;
    const float4 G1 = ldok ? *(const float4*)(gp1 + off) : Z4;
    const float4 G2 = ldok ? *(const float4*)(gp2 + off) : Z4;
    const float4 S0 = ldok ? *(const float4*)(sp0 + off) : Z4;
    const float4 S1 = ldok ? *(const float4*)(sp1 + off) : Z4;
    const float4 S2 = ldok ? *(const float4*)(sp2 + off) : Z4;
    const float4 S3 = ldok ? *(const float4*)(sp3 + off) : Z4;
    const float g0v[4] = {G0.x, G0.y, G0.z, G0.w};
    const float g1v[4] = {G1.x, G1.y, G1.z, G1.w};
    const float g2v[4] = {G2.x, G2.y, G2.z, G2.w};
    const float s0v[4] = {S0.x, S0.y, S0.z, S0.w};
    const float s1v[4] = {S1.x, S1.y, S1.z, S1.w};
    const float s2v[4] = {S2.x, S2.y, S2.z, S2.w};
    const float s3v[4] = {S3.x, S3.y, S3.z, S3.w};
#pragma unroll
    for (int j = 0; j < 4; ++j) {
      s[0][j] += g0v[j]; s[1][j] += g1v[j]; s[2][j] += g2v[j];
      s[3][j] += s0v[j]; s[4][j] += s1v[j]; s[5][j] += s2v[j]; s[6][j] += s3v[j];
      s[7][j]  += g0v[j] * s0v[j]; s[8][j]  += g0v[j] * s1v[j];
      s[9][j]  += g0v[j] * s2v[j]; s[10][j] += g0v[j] * s3v[j];
      s[11][j] += g1v[j] * s0v[j]; s[12][j] += g1v[j] * s1v[j];
      s[13][j] += g1v[j] * s2v[j]; s[14][j] += g1v[j] * s3v[j];
      s[15][j] += g2v[j] * s0v[j]; s[16][j] += g2v[j] * s1v[j];
      s[17][j] += g2v[j] * s2v[j]; s[18][j] += g2v[j] * s3v[j];
      s[19][j] += g0v[j] * g0v[j]; s[20][j] += g0v[j] * g1v[j];
      s[21][j] += g0v[j] * g2v[j]; s[22][j] += g1v[j] * g1v[j];
      s[23][j] += g1v[j] * g2v[j]; s[24][j] += g2v[j] * g2v[j];
    }
  }

  const int ny = min(row + RAD, HH - 1) - max(row - RAD, 0) + 1;
  const float invny = 1.0f / (float)ny;
  const int cbase = E + 12 + 4 * lane;  // this thread's a/b col base
  float invN[4];
#pragma unroll
  for (int j = 0; j < 4; ++j) {
    const int c = cbase + j;
    const int nx = min(c + RAD, WW - 1) - max(c - RAD, 0) + 1;
    invN[j] = invny / (float)nx;
  }
  const bool abok = (lane <= 58) && (cbase >= 0) && (cbase < WW);

  // horizontal box of one vertically-boxed channel at this thread's 4 cols
  auto hboxS = [&](const float sv[4], float out[4]) {
    const float s1 = sv[0] + sv[1], s2 = s1 + sv[2], ts = s2 + sv[3];
    const float incl = wave_incl_scan(ts);
    const float base = incl - ts;
    const float P0 = base + sv[0], P1 = base + s1, P2 = base + s2, P3 = incl;
    const float PW = __shfl(P3, min(relmax >> 2, 63));
    const float hh[4] = {__shfl(P0, lane + 5), __shfl(P1, lane + 5),
                         __shfl(P2, lane + 5), __shfl(P3, lane + 5)};
    const float ll[4] = {P3, __shfl(P0, lane + 1), __shfl(P1, lane + 1),
                         __shfl(P2, lane + 1)};
    const int r0 = 4 * lane + 12;
#pragma unroll
    for (int j = 0; j < 4; ++j) {
      const float hi = (r0 + j + 8 <= relmax) ? hh[j] : PW;
      const float lo = (E + r0 + j >= 9) ? ll[j] : 0.f;
      out[j] = hi - lo;
    }
  };

  // guide means
  float mI[3][4];
#pragma unroll
  for (int k = 0; k < 3; ++k) {
    float t[4];
    hboxS(s[k], t);
#pragma unroll
    for (int j = 0; j < 4; ++j) mI[k][j] = t[j] * invN[j];
  }
  // covariance of guide -> inverse (symmetric 3x3)
  float inv[6][4];
  {
    float v19[4], v20[4], v21[4], v22[4], v23[4], v24[4];
    hboxS(s[19], v19); hboxS(s[20], v20); hboxS(s[21], v21);
    hboxS(s[22], v22); hboxS(s[23], v23); hboxS(s[24], v24);
#pragma unroll
    for (int j = 0; j < 4; ++j) {
      const float rr = v19[j] * invN[j] - mI[0][j] * mI[0][j] + EPSF;
      const float rg = v20[j] * invN[j] - mI[0][j] * mI[1][j];
      const float rb = v21[j] * invN[j] - mI[0][j] * mI[2][j];
      const float gg = v22[j] * invN[j] - mI[1][j] * mI[1][j] + EPSF;
      const float gb = v23[j] * invN[j] - mI[1][j] * mI[2][j];
      const float bb = v24[j] * invN[j] - mI[2][j] * mI[2][j] + EPSF;
      const float det = rr * gg * bb + 2.f * rg * gb * rb
                      - rb * gg * rb - rg * rg * bb - rr * gb * gb;
      const float idet = 1.0f / det;
      inv[0][j] = (gg * bb - gb * gb) * idet;
      inv[1][j] = (rb * gb - rg * bb) * idet;
      inv[2][j] = (rg * gb - rb * gg) * idet;
      inv[3][j] = (rr * bb - rb * rb) * idet;
      inv[4][j] = (rb * rg - rr * gb) * idet;
      inv[5][j] = (rr * gg - rg * rg) * idet;
    }
  }

  // phase B parameters
  const int qmax = relmax - 12;
  const int nstore = min(54, (WW - F) >> 2);
  const bool stok = lane < nstore;
  const size_t obase = (size_t)row * WW + F + 4 * lane;

  // phase-B hbox over a/b from registers -> store one plane
  auto phaseB = [&](const float vv[4], int plane) {
    const float s1 = vv[0] + vv[1], s2 = s1 + vv[2], ts = s2 + vv[3];
    const float incl = wave_incl_scan(ts);
    const float base = incl - ts;
    const float Q0 = base + vv[0], Q1 = base + s1, Q2 = base + s2, Q3 = incl;
    const float PW2 = __shfl(Q3, min(qmax >> 2, 63));
    const float hh[4] = {__shfl(Q0, lane + 4), __shfl(Q1, lane + 4),
                         __shfl(Q2, lane + 4), __shfl(Q3, lane + 4)};
    const float lm1 = __shfl(Q3, lane - 1);
    const float ll[4] = {lm1, Q0, Q1, Q2};
    const int qf0 = 8 + 4 * lane;
    float o[4];
#pragma unroll
    for (int j = 0; j < 4; ++j) {
      const float hi = (qf0 + j + 8 <= qmax) ? hh[j] : PW2;
      const float lo = (qf0 + j >= 9) ? ll[j] : 0.f;
      o[j] = hi - lo;
    }
    if (stok)
      *(float4*)(wsb + (size_t)plane * HWSZ + obase) =
          make_float4(o[0], o[1], o[2], o[3]);
  };

  // per-src-channel: solve -> a0,a1,a2,b, immediately phase-B + store
#pragma unroll
  for (int cc = 0; cc < 4; ++cc) {
    float mp[4], q0[4], q1[4], q2[4];
    hboxS(s[3 + cc], mp);
    hboxS(s[7 + cc], q0);
    hboxS(s[11 + cc], q1);
    hboxS(s[15 + cc], q2);
    float a0v[4], a1v[4], a2v[4], bv[4];
#pragma unroll
    for (int j = 0; j < 4; ++j) {
      const float m = mp[j] * invN[j];
      const float c0v = q0[j] * invN[j] - mI[0][j] * m;
      const float c1v = q1[j] * invN[j] - mI[1][j] * m;
      const float c2v = q2[j] * invN[j] - mI[2][j] * m;
      const float a0 = c0v * inv[0][j] + c1v * inv[1][j] + c2v * inv[2][j];
      const float a1 = c0v * inv[1][j] + c1v * inv[3][j] + c2v * inv[4][j];
      const float a2 = c0v * inv[2][j] + c1v * inv[4][j] + c2v * inv[5][j];
      const float b_ = m - (a0 * mI[0][j] + a1 * mI[1][j] + a2 * mI[2][j]);
      a0v[j] = abok ? a0 : 0.f;
      a1v[j] = abok ? a1 : 0.f;
      a2v[j] = abok ? a2 : 0.f;
      bv[j]  = abok ? b_ : 0.f;
    }
    phaseB(a0v, cc);
    phaseB(a1v, 4 + cc);
    phaseB(a2v, 8 + cc);
    phaseB(bv, 12 + cc);
  }
}

// ---------------- K_B: vertical box of boxed a/b + combine with guide -> q
__global__ __launch_bounds__(64) void k_vbox_comb(const float* __restrict__ ws_,
                                                  const float* __restrict__ g,
                                                  float* __restrict__ out, int b0) {
  const int c0 = blockIdx.x * 128 + threadIdx.x * 2;
  const int y0 = blockIdx.y * V3R;
  const int b = b0 + blockIdx.z;
  const float* wsb = ws_ + (size_t)blockIdx.z * NPLB * HWSZ;
  const float* gp0 = g + (size_t)(b * 3 + 0) * HWSZ;
  const float* gp1 = g + (size_t)(b * 3 + 1) * HWSZ;
  const float* gp2 = g + (size_t)(b * 3 + 2) * HWSZ;
  float* op0 = out + (size_t)(b * 4 + 0) * HWSZ;
  float* op1 = out + (size_t)(b * 4 + 1) * HWSZ;
  float* op2 = out + (size_t)(b * 4 + 2) * HWSZ;
  float* op3 = out + (size_t)(b * 4 + 3) * HWSZ;

  float acc[16][2];
#pragma unroll
  for (int i = 0; i < 16; ++i) { acc[i][0] = 0.f; acc[i][1] = 0.f; }

  auto row_op = [&](int y, bool add) {
    const int off = y * WW + c0;
#pragma unroll
    for (int i = 0; i < 16; ++i) {
      const float2 v = *(const float2*)(wsb + (size_t)i * HWSZ + off);
      if (add) { acc[i][0] += v.x; acc[i][1] += v.y; }
      else     { acc[i][0] -= v.x; acc[i][1] -= v.y; }
    }
  };

  for (int yy = y0 - RAD; yy <= y0 + RAD; ++yy)
    if (yy >= 0 && yy < HH) row_op(yy, true);

  float invnx[2];
#pragma unroll
  for (int k = 0; k < 2; ++k) {
    const int c = c0 + k;
    const int nx = min(c + RAD, WW - 1) - max(c - RAD, 0) + 1;
    invnx[k] = 1.0f / (float)nx;
  }

  for (int y = y0; y < y0 + V3R; ++y) {
    const int ny = min(y + RAD, HH - 1) - max(y - RAD, 0) + 1;
    const float invny = 1.0f / (float)ny;
    const size_t off = (size_t)y * WW + c0;
    const float2 G0 = *(const float2*)(gp0 + off);
    const float2 G1 = *(const float2*)(gp1 + off);
    const float2 G2 = *(const float2*)(gp2 + off);
    const float gk0[2] = {G0.x, G0.y}, gk1[2] = {G1.x, G1.y}, gk2[2] = {G2.x, G2.y};
    float o0[2], o1[2], o2[2], o3[2];
#pragma unroll
    for (int k = 0; k < 2; ++k) {
      const float invN = invnx[k] * invny;
      o0[k] = (acc[0][k] * gk0[k] + acc[4][k] * gk1[k] + acc[8][k]  * gk2[k] + acc[12][k]) * invN;
      o1[k] = (acc[1][k] * gk0[k] + acc[5][k] * gk1[k] + acc[9][k]  * gk2[k] + acc[13][k]) * invN;
      o2[k] = (acc[2][k] * gk0[k] + acc[6][k] * gk1[k] + acc[10][k] * gk2[k] + acc[14][k]) * invN;
      o3[k] = (acc[3][k] * gk0[k] + acc[7][k] * gk1[k] + acc[11][k] * gk2[k] + acc[15][k]) * invN;
    }
    *(float2*)(op0 + off) = make_float2(o0[0], o0[1]);
    *(float2*)(op1 + off) = make_float2(o1[0], o1[1]);
    *(float2*)(op2 + off) = make_float2(o2[0], o2[1]);
    *(float2*)(op3 + off) = make_float2(o3[0], o3[1]);
    const int ye = y + RAD + 1;
    if (ye < HH) row_op(ye, true);
    const int yl = y - RAD;
    if (yl >= 0) row_op(yl, false);
  }
}

extern "C" void kernel_launch(void* const* d_in, const int* in_sizes, int n_in,
                              void* d_out, int out_size, void* d_ws, size_t ws_size,
                              hipStream_t stream) {
  const float* x = (const float*)d_in[0];   // (4,4,1024,1024) src p
  const float* g = (const float*)d_in[1];   // (4,3,1024,1024) guide
  float* out = (float*)d_out;
  float* ws = (float*)d_ws;
  const size_t perBatchBytes = (size_t)NPLB * HWSZ * sizeof(float);  // 64 MB
  int nb = (int)(ws_size / perBatchBytes);
  if (nb < 1) nb = 1;
  if (nb > 4) nb = 4;
  for (int b0 = 0; b0 < 4; b0 += nb) {
    const int nbc = (4 - b0 < nb) ? (4 - b0) : nb;
    dim3 gA(HH * NTL / 4, nbc);
    dim3 gB(WW / 128, HH / V3R, nbc);
    hipLaunchKernelGGL(k_stats_solve, gA, dim3(256), 0, stream, x, g, ws, b0);
    hipLaunchKernelGGL(k_vbox_comb, gB, dim3(64), 0, stream, ws, g, out, b0);
  }
}

// Round 7
// 527.723 us; speedup vs baseline: 1.5413x; 1.5413x over previous
//
#include <hip/hip_runtime.h>

#define HH 1024
#define WW 1024
#define RAD 8
#define EPSF 1e-4f
#define HWSZ (HH * WW)
#define NPLB 16  // ws planes per batch (boxed a/b only)
#define T2 216   // output cols per wave
#define NTL 5    // tiles per row (216*5 = 1080 >= 1024)
#define RROWS 8  // rows per wave, k_stats_solve (sliding window)
#define V3R 8    // rows per block, k_vbox_comb

__device__ __forceinline__ float4 f4add(float4 a, float4 b) {
  return make_float4(a.x + b.x, a.y + b.y, a.z + b.z, a.w + b.w);
}
__device__ __forceinline__ float4 f4sub(float4 a, float4 b) {
  return make_float4(a.x - b.x, a.y - b.y, a.z - b.z, a.w - b.w);
}
__device__ __forceinline__ float4 f4mul(float4 a, float4 b) {
  return make_float4(a.x * b.x, a.y * b.y, a.z * b.z, a.w * b.w);
}

// Inclusive wave64 prefix scan via DPP (VALU-only, no LDS pipe).
__device__ __forceinline__ float wave_incl_scan(float v) {
  int t;
  t = __builtin_amdgcn_update_dpp(0, __float_as_int(v), 0x111, 0xf, 0xf, false);
  v += __int_as_float(t);
  t = __builtin_amdgcn_update_dpp(0, __float_as_int(v), 0x112, 0xf, 0xf, false);
  v += __int_as_float(t);
  t = __builtin_amdgcn_update_dpp(0, __float_as_int(v), 0x114, 0xf, 0xf, false);
  v += __int_as_float(t);
  t = __builtin_amdgcn_update_dpp(0, __float_as_int(v), 0x118, 0xf, 0xf, false);
  v += __int_as_float(t);
  t = __builtin_amdgcn_update_dpp(0, __float_as_int(v), 0x142, 0xa, 0xf, false);
  v += __int_as_float(t);
  t = __builtin_amdgcn_update_dpp(0, __float_as_int(v), 0x143, 0xc, 0xf, false);
  v += __int_as_float(t);
  return v;
}

// ---------------- K_A: sliding vbox(25 products) + hbox(25) + 3x3 solve
// + hbox(a/b) -> 16 boxed-a/b planes. One wave per (tile, 8-row block).
// Cols [E, E+256) per wave, outputs at [F, F+216). All per-channel state
// is float4 by VALUE (SROA-safe); vertical sums slide (+row(r+9), -row(r-8)).
__global__ __launch_bounds__(256, 2) void k_stats_solve(
    const float* __restrict__ x, const float* __restrict__ g,
    float* __restrict__ ws, int b0) {
  const int lane = threadIdx.x & 63;
  const int w = threadIdx.x >> 6;
  const int bi = blockIdx.y;
  const int gw = blockIdx.x * 4 + w;  // 0 .. (HH/RROWS)*NTL - 1
  const int rowblk = gw / NTL;
  const int tix = gw - rowblk * NTL;
  const int y0 = rowblk * RROWS;
  const int b = b0 + bi;
  float* wsb = ws + (size_t)bi * NPLB * HWSZ;
  const int F = tix * T2;
  const int E = F - 20;
  const int relmax = (WW - 1) - E;
  const int col0 = E + 4 * lane;
  const bool ldok = (col0 >= 0) && (col0 < WW);

  const float* gp0 = g + (size_t)(b * 3 + 0) * HWSZ;
  const float* gp1 = g + (size_t)(b * 3 + 1) * HWSZ;
  const float* gp2 = g + (size_t)(b * 3 + 2) * HWSZ;
  const float* sp0 = x + (size_t)(b * 4 + 0) * HWSZ;
  const float* sp1 = x + (size_t)(b * 4 + 1) * HWSZ;
  const float* sp2 = x + (size_t)(b * 4 + 2) * HWSZ;
  const float* sp3 = x + (size_t)(b * 4 + 3) * HWSZ;

  const int cbase = E + 12 + 4 * lane;
  float nxinv[4];
#pragma unroll
  for (int j = 0; j < 4; ++j) {
    const int c = cbase + j;
    const int nx = min(c + RAD, WW - 1) - max(c - RAD, 0) + 1;
    nxinv[j] = 1.0f / (float)nx;
  }
  const bool abok = (lane <= 58) && (cbase >= 0) && (cbase < WW);
  const int qmax = relmax - 12;
  const int nstore = min(54, (WW - F) >> 2);
  const bool stok = lane < nstore;

  // sliding vertical sums of the 25 product channels (float4 = 4 cols)
  float4 s[25];
#pragma unroll
  for (int i = 0; i < 25; ++i) s[i] = make_float4(0.f, 0.f, 0.f, 0.f);

  const float4 Z4 = make_float4(0.f, 0.f, 0.f, 0.f);

  auto row_acc = [&](int yy, bool add) {
    if (yy < 0 || yy >= HH) return;
    const int off = yy * WW + col0;
    const float4 G0 = ldok ? *(const float4*)(gp0 + off) : Z4;
    const float4 G1 = ldok ? *(const float4*)(gp1 + off) : Z4;
    const float4 G2 = ldok ? *(const float4*)(gp2 + off) : Z4;
    const float4 S0 = ldok ? *(const float4*)(sp0 + off) : Z4;
    const float4 S1 = ldok ? *(const float4*)(sp1 + off) : Z4;
    const float4 S2 = ldok ? *(const float4*)(sp2 + off) : Z4;
    const float4 S3 = ldok ? *(const float4*)(sp3 + off) : Z4;
#define ACC(idx, val)                          \
  do {                                         \
    const float4 t_ = (val);                   \
    s[idx] = add ? f4add(s[idx], t_) : f4sub(s[idx], t_); \
  } while (0)
    ACC(0, G0); ACC(1, G1); ACC(2, G2);
    ACC(3, S0); ACC(4, S1); ACC(5, S2); ACC(6, S3);
    ACC(7, f4mul(G0, S0)); ACC(8, f4mul(G0, S1));
    ACC(9, f4mul(G0, S2)); ACC(10, f4mul(G0, S3));
    ACC(11, f4mul(G1, S0)); ACC(12, f4mul(G1, S1));
    ACC(13, f4mul(G1, S2)); ACC(14, f4mul(G1, S3));
    ACC(15, f4mul(G2, S0)); ACC(16, f4mul(G2, S1));
    ACC(17, f4mul(G2, S2)); ACC(18, f4mul(G2, S3));
    ACC(19, f4mul(G0, G0)); ACC(20, f4mul(G0, G1)); ACC(21, f4mul(G0, G2));
    ACC(22, f4mul(G1, G1)); ACC(23, f4mul(G1, G2)); ACC(24, f4mul(G2, G2));
#undef ACC
  };

  // horizontal box of one vertically-boxed channel (by value, SROA-safe)
  auto hbox4 = [&](float4 sv) -> float4 {
    const float s1 = sv.x + sv.y, s2 = s1 + sv.z, ts = s2 + sv.w;
    const float incl = wave_incl_scan(ts);
    const float base = incl - ts;
    const float P0 = base + sv.x, P1 = base + s1, P2 = base + s2, P3 = incl;
    const float PW = __shfl(P3, min(relmax >> 2, 63));
    const float h0 = __shfl(P0, lane + 5), h1 = __shfl(P1, lane + 5);
    const float h2 = __shfl(P2, lane + 5), h3 = __shfl(P3, lane + 5);
    const float l1 = __shfl(P0, lane + 1), l2 = __shfl(P1, lane + 1);
    const float l3 = __shfl(P2, lane + 1);
    const int r0 = 4 * lane + 12;
    float4 o;
    o.x = ((r0 + 8 <= relmax) ? h0 : PW) - ((E + r0 >= 9) ? P3 : 0.f);
    o.y = ((r0 + 9 <= relmax) ? h1 : PW) - ((E + r0 + 1 >= 9) ? l1 : 0.f);
    o.z = ((r0 + 10 <= relmax) ? h2 : PW) - ((E + r0 + 2 >= 9) ? l2 : 0.f);
    o.w = ((r0 + 11 <= relmax) ? h3 : PW) - ((E + r0 + 3 >= 9) ? l3 : 0.f);
    return o;
  };

  // init window for first row
  for (int yy = y0 - RAD; yy <= y0 + RAD; ++yy) row_acc(yy, true);

  for (int row = y0; row < y0 + RROWS; ++row) {
    const int ny = min(row + RAD, HH - 1) - max(row - RAD, 0) + 1;
    const float invny = 1.0f / (float)ny;
    float invN[4];
#pragma unroll
    for (int j = 0; j < 4; ++j) invN[j] = invny * nxinv[j];

    // guide means
    float mI[3][4];
#pragma unroll
    for (int k = 0; k < 3; ++k) {
      const float4 t = hbox4(s[k]);
      mI[k][0] = t.x * invN[0]; mI[k][1] = t.y * invN[1];
      mI[k][2] = t.z * invN[2]; mI[k][3] = t.w * invN[3];
    }
    // covariance of guide -> inverse (symmetric 3x3)
    float inv[6][4];
    {
      const float4 t19 = hbox4(s[19]), t20 = hbox4(s[20]), t21 = hbox4(s[21]);
      const float4 t22 = hbox4(s[22]), t23 = hbox4(s[23]), t24 = hbox4(s[24]);
      const float v19[4] = {t19.x, t19.y, t19.z, t19.w};
      const float v20[4] = {t20.x, t20.y, t20.z, t20.w};
      const float v21[4] = {t21.x, t21.y, t21.z, t21.w};
      const float v22[4] = {t22.x, t22.y, t22.z, t22.w};
      const float v23[4] = {t23.x, t23.y, t23.z, t23.w};
      const float v24[4] = {t24.x, t24.y, t24.z, t24.w};
#pragma unroll
      for (int j = 0; j < 4; ++j) {
        const float rr = v19[j] * invN[j] - mI[0][j] * mI[0][j] + EPSF;
        const float rg = v20[j] * invN[j] - mI[0][j] * mI[1][j];
        const float rb = v21[j] * invN[j] - mI[0][j] * mI[2][j];
        const float gg = v22[j] * invN[j] - mI[1][j] * mI[1][j] + EPSF;
        const float gb = v23[j] * invN[j] - mI[1][j] * mI[2][j];
        const float bb = v24[j] * invN[j] - mI[2][j] * mI[2][j] + EPSF;
        const float det = rr * gg * bb + 2.f * rg * gb * rb
                        - rb * gg * rb - rg * rg * bb - rr * gb * gb;
        const float idet = 1.0f / det;
        inv[0][j] = (gg * bb - gb * gb) * idet;
        inv[1][j] = (rb * gb - rg * bb) * idet;
        inv[2][j] = (rg * gb - rb * gg) * idet;
        inv[3][j] = (rr * bb - rb * rb) * idet;
        inv[4][j] = (rb * rg - rr * gb) * idet;
        inv[5][j] = (rr * gg - rg * rg) * idet;
      }
    }

    const size_t obase = (size_t)row * WW + F + 4 * lane;
    // phase-B hbox over a/b from registers -> store one plane
    auto phaseB = [&](float4 vv, int plane) {
      const float s1 = vv.x + vv.y, s2 = s1 + vv.z, ts = s2 + vv.w;
      const float incl = wave_incl_scan(ts);
      const float base = incl - ts;
      const float Q0 = base + vv.x, Q1 = base + s1, Q2 = base + s2, Q3 = incl;
      const float PW2 = __shfl(Q3, min(qmax >> 2, 63));
      const float h0 = __shfl(Q0, lane + 4), h1 = __shfl(Q1, lane + 4);
      const float h2 = __shfl(Q2, lane + 4), h3 = __shfl(Q3, lane + 4);
      const float lm1 = __shfl(Q3, lane - 1);
      const int qf0 = 8 + 4 * lane;
      float4 o;
      o.x = ((qf0 + 8 <= qmax) ? h0 : PW2) - ((qf0 >= 9) ? lm1 : 0.f);
      o.y = ((qf0 + 9 <= qmax) ? h1 : PW2) - Q0;  // qf0+1 >= 9 always
      o.z = ((qf0 + 10 <= qmax) ? h2 : PW2) - Q1;
      o.w = ((qf0 + 11 <= qmax) ? h3 : PW2) - Q2;
      if (stok) *(float4*)(wsb + (size_t)plane * HWSZ + obase) = o;
    };

    // per-src-channel: solve -> a0,a1,a2,b, then phase-B + store
#pragma unroll
    for (int cc = 0; cc < 4; ++cc) {
      const float4 tmp = hbox4(s[3 + cc]);
      const float4 tq0 = hbox4(s[7 + cc]);
      const float4 tq1 = hbox4(s[11 + cc]);
      const float4 tq2 = hbox4(s[15 + cc]);
      const float mp[4] = {tmp.x, tmp.y, tmp.z, tmp.w};
      const float q0[4] = {tq0.x, tq0.y, tq0.z, tq0.w};
      const float q1[4] = {tq1.x, tq1.y, tq1.z, tq1.w};
      const float q2[4] = {tq2.x, tq2.y, tq2.z, tq2.w};
      float4 a0v, a1v, a2v, bv;
      float* pa0 = &a0v.x; float* pa1 = &a1v.x;
      float* pa2 = &a2v.x; float* pbv = &bv.x;
#pragma unroll
      for (int j = 0; j < 4; ++j) {
        const float m = mp[j] * invN[j];
        const float c0v = q0[j] * invN[j] - mI[0][j] * m;
        const float c1v = q1[j] * invN[j] - mI[1][j] * m;
        const float c2v = q2[j] * invN[j] - mI[2][j] * m;
        const float a0 = c0v * inv[0][j] + c1v * inv[1][j] + c2v * inv[2][j];
        const float a1 = c0v * inv[1][j] + c1v * inv[3][j] + c2v * inv[4][j];
        const float a2 = c0v * inv[2][j] + c1v * inv[4][j] + c2v * inv[5][j];
        const float b_ = m - (a0 * mI[0][j] + a1 * mI[1][j] + a2 * mI[2][j]);
        pa0[j] = abok ? a0 : 0.f;
        pa1[j] = abok ? a1 : 0.f;
        pa2[j] = abok ? a2 : 0.f;
        pbv[j] = abok ? b_ : 0.f;
      }
      phaseB(a0v, cc);
      phaseB(a1v, 4 + cc);
      phaseB(a2v, 8 + cc);
      phaseB(bv, 12 + cc);
    }

    // slide window: +row(row+9), -row(row-8)
    row_acc(row + RAD + 1, true);
    row_acc(row - RAD, false);
  }
}

// ---------------- K_B: vertical box of boxed a/b + combine with guide -> q
__global__ __launch_bounds__(64) void k_vbox_comb(const float* __restrict__ ws_,
                                                  const float* __restrict__ g,
                                                  float* __restrict__ out, int b0) {
  const int c0 = blockIdx.x * 128 + threadIdx.x * 2;
  const int y0 = blockIdx.y * V3R;
  const int b = b0 + blockIdx.z;
  const float* wsb = ws_ + (size_t)blockIdx.z * NPLB * HWSZ;
  const float* gp0 = g + (size_t)(b * 3 + 0) * HWSZ;
  const float* gp1 = g + (size_t)(b * 3 + 1) * HWSZ;
  const float* gp2 = g + (size_t)(b * 3 + 2) * HWSZ;
  float* op0 = out + (size_t)(b * 4 + 0) * HWSZ;
  float* op1 = out + (size_t)(b * 4 + 1) * HWSZ;
  float* op2 = out + (size_t)(b * 4 + 2) * HWSZ;
  float* op3 = out + (size_t)(b * 4 + 3) * HWSZ;

  float acc[16][2];
#pragma unroll
  for (int i = 0; i < 16; ++i) { acc[i][0] = 0.f; acc[i][1] = 0.f; }

  auto row_op = [&](int y, bool add) {
    const int off = y * WW + c0;
#pragma unroll
    for (int i = 0; i < 16; ++i) {
      const float2 v = *(const float2*)(wsb + (size_t)i * HWSZ + off);
      if (add) { acc[i][0] += v.x; acc[i][1] += v.y; }
      else     { acc[i][0] -= v.x; acc[i][1] -= v.y; }
    }
  };

  for (int yy = y0 - RAD; yy <= y0 + RAD; ++yy)
    if (yy >= 0 && yy < HH) row_op(yy, true);

  float invnx[2];
#pragma unroll
  for (int k = 0; k < 2; ++k) {
    const int c = c0 + k;
    const int nx = min(c + RAD, WW - 1) - max(c - RAD, 0) + 1;
    invnx[k] = 1.0f / (float)nx;
  }

  for (int y = y0; y < y0 + V3R; ++y) {
    const int ny = min(y + RAD, HH - 1) - max(y - RAD, 0) + 1;
    const float invny = 1.0f / (float)ny;
    const size_t off = (size_t)y * WW + c0;
    const float2 G0 = *(const float2*)(gp0 + off);
    const float2 G1 = *(const float2*)(gp1 + off);
    const float2 G2 = *(const float2*)(gp2 + off);
    const float gk0[2] = {G0.x, G0.y}, gk1[2] = {G1.x, G1.y}, gk2[2] = {G2.x, G2.y};
    float o0[2], o1[2], o2[2], o3[2];
#pragma unroll
    for (int k = 0; k < 2; ++k) {
      const float invN = invnx[k] * invny;
      o0[k] = (acc[0][k] * gk0[k] + acc[4][k] * gk1[k] + acc[8][k]  * gk2[k] + acc[12][k]) * invN;
      o1[k] = (acc[1][k] * gk0[k] + acc[5][k] * gk1[k] + acc[9][k]  * gk2[k] + acc[13][k]) * invN;
      o2[k] = (acc[2][k] * gk0[k] + acc[6][k] * gk1[k] + acc[10][k] * gk2[k] + acc[14][k]) * invN;
      o3[k] = (acc[3][k] * gk0[k] + acc[7][k] * gk1[k] + acc[11][k] * gk2[k] + acc[15][k]) * invN;
    }
    *(float2*)(op0 + off) = make_float2(o0[0], o0[1]);
    *(float2*)(op1 + off) = make_float2(o1[0], o1[1]);
    *(float2*)(op2 + off) = make_float2(o2[0], o2[1]);
    *(float2*)(op3 + off) = make_float2(o3[0], o3[1]);
    const int ye = y + RAD + 1;
    if (ye < HH) row_op(ye, true);
    const int yl = y - RAD;
    if (yl >= 0) row_op(yl, false);
  }
}

extern "C" void kernel_launch(void* const* d_in, const int* in_sizes, int n_in,
                              void* d_out, int out_size, void* d_ws, size_t ws_size,
                              hipStream_t stream) {
  const float* x = (const float*)d_in[0];   // (4,4,1024,1024) src p
  const float* g = (const float*)d_in[1];   // (4,3,1024,1024) guide
  float* out = (float*)d_out;
  float* ws = (float*)d_ws;
  const size_t perBatchBytes = (size_t)NPLB * HWSZ * sizeof(float);  // 64 MB
  int nb = (int)(ws_size / perBatchBytes);
  if (nb < 1) nb = 1;
  if (nb > 4) nb = 4;
  for (int b0 = 0; b0 < 4; b0 += nb) {
    const int nbc = (4 - b0 < nb) ? (4 - b0) : nb;
    dim3 gA((HH / RROWS) * NTL / 4, nbc);
    dim3 gB(WW / 128, HH / V3R, nbc);
    hipLaunchKernelGGL(k_stats_solve, gA, dim3(256), 0, stream, x, g, ws, b0);
    hipLaunchKernelGGL(k_vbox_comb, gB, dim3(64), 0, stream, ws, g, out, b0);
  }
}

// Round 8
// 514.583 us; speedup vs baseline: 1.5807x; 1.0255x over previous
//
#include <hip/hip_runtime.h>

#define HH 1024
#define WW 1024
#define RAD 8
#define EPSF 1e-4f
#define HWSZ (HH * WW)
#define NPLB 16  // ws planes per batch (boxed a/b only)
#define T2 216   // output cols per wave
#define NTL 5    // tiles per row (216*5 = 1080 >= 1024)
#define RROWS 4  // rows per wave, k_stats_solve (sliding window)
#define V3R 32   // rows per block, k_vbox_comb (sliding, thread-per-col)

__device__ __forceinline__ float4 f4add(float4 a, float4 b) {
  return make_float4(a.x + b.x, a.y + b.y, a.z + b.z, a.w + b.w);
}
__device__ __forceinline__ float4 f4sub(float4 a, float4 b) {
  return make_float4(a.x - b.x, a.y - b.y, a.z - b.z, a.w - b.w);
}
__device__ __forceinline__ float4 f4mul(float4 a, float4 b) {
  return make_float4(a.x * b.x, a.y * b.y, a.z * b.z, a.w * b.w);
}

// Inclusive wave64 prefix scan via DPP (VALU-only, no LDS pipe).
__device__ __forceinline__ float wave_incl_scan(float v) {
  int t;
  t = __builtin_amdgcn_update_dpp(0, __float_as_int(v), 0x111, 0xf, 0xf, false);
  v += __int_as_float(t);
  t = __builtin_amdgcn_update_dpp(0, __float_as_int(v), 0x112, 0xf, 0xf, false);
  v += __int_as_float(t);
  t = __builtin_amdgcn_update_dpp(0, __float_as_int(v), 0x114, 0xf, 0xf, false);
  v += __int_as_float(t);
  t = __builtin_amdgcn_update_dpp(0, __float_as_int(v), 0x118, 0xf, 0xf, false);
  v += __int_as_float(t);
  t = __builtin_amdgcn_update_dpp(0, __float_as_int(v), 0x142, 0xa, 0xf, false);
  v += __int_as_float(t);
  t = __builtin_amdgcn_update_dpp(0, __float_as_int(v), 0x143, 0xc, 0xf, false);
  v += __int_as_float(t);
  return v;
}

// ---------------- K_A: sliding vbox(25 products) + hbox(25) + 3x3 solve
// + hbox(a/b) -> 16 boxed-a/b planes. One wave per (tile, RROWS-row block).
__global__ __launch_bounds__(256, 2) void k_stats_solve(
    const float* __restrict__ x, const float* __restrict__ g,
    float* __restrict__ ws, int b0) {
  const int lane = threadIdx.x & 63;
  const int w = threadIdx.x >> 6;
  const int bi = blockIdx.y;
  const int gw = blockIdx.x * 4 + w;  // 0 .. (HH/RROWS)*NTL - 1
  const int rowblk = gw / NTL;
  const int tix = gw - rowblk * NTL;
  const int y0 = rowblk * RROWS;
  const int b = b0 + bi;
  float* wsb = ws + (size_t)bi * NPLB * HWSZ;
  const int F = tix * T2;
  const int E = F - 20;
  const int relmax = (WW - 1) - E;
  const int col0 = E + 4 * lane;
  const bool ldok = (col0 >= 0) && (col0 < WW);

  const float* gp0 = g + (size_t)(b * 3 + 0) * HWSZ;
  const float* gp1 = g + (size_t)(b * 3 + 1) * HWSZ;
  const float* gp2 = g + (size_t)(b * 3 + 2) * HWSZ;
  const float* sp0 = x + (size_t)(b * 4 + 0) * HWSZ;
  const float* sp1 = x + (size_t)(b * 4 + 1) * HWSZ;
  const float* sp2 = x + (size_t)(b * 4 + 2) * HWSZ;
  const float* sp3 = x + (size_t)(b * 4 + 3) * HWSZ;

  const int cbase = E + 12 + 4 * lane;
  float nxinv[4];
#pragma unroll
  for (int j = 0; j < 4; ++j) {
    const int c = cbase + j;
    const int nx = min(c + RAD, WW - 1) - max(c - RAD, 0) + 1;
    nxinv[j] = 1.0f / (float)nx;
  }
  const bool abok = (lane <= 58) && (cbase >= 0) && (cbase < WW);
  const int qmax = relmax - 12;
  const int nstore = min(54, (WW - F) >> 2);
  const bool stok = lane < nstore;

  // sliding vertical sums of the 25 product channels (float4 = 4 cols)
  float4 s[25];
#pragma unroll
  for (int i = 0; i < 25; ++i) s[i] = make_float4(0.f, 0.f, 0.f, 0.f);

  const float4 Z4 = make_float4(0.f, 0.f, 0.f, 0.f);

  auto row_acc = [&](int yy, bool add) {
    if (yy < 0 || yy >= HH) return;
    const int off = yy * WW + col0;
    const float4 G0 = ldok ? *(const float4*)(gp0 + off) : Z4;
    const float4 G1 = ldok ? *(const float4*)(gp1 + off) : Z4;
    const float4 G2 = ldok ? *(const float4*)(gp2 + off) : Z4;
    const float4 S0 = ldok ? *(const float4*)(sp0 + off) : Z4;
    const float4 S1 = ldok ? *(const float4*)(sp1 + off) : Z4;
    const float4 S2 = ldok ? *(const float4*)(sp2 + off) : Z4;
    const float4 S3 = ldok ? *(const float4*)(sp3 + off) : Z4;
#define ACC(idx, val)                          \
  do {                                         \
    const float4 t_ = (val);                   \
    s[idx] = add ? f4add(s[idx], t_) : f4sub(s[idx], t_); \
  } while (0)
    ACC(0, G0); ACC(1, G1); ACC(2, G2);
    ACC(3, S0); ACC(4, S1); ACC(5, S2); ACC(6, S3);
    ACC(7, f4mul(G0, S0)); ACC(8, f4mul(G0, S1));
    ACC(9, f4mul(G0, S2)); ACC(10, f4mul(G0, S3));
    ACC(11, f4mul(G1, S0)); ACC(12, f4mul(G1, S1));
    ACC(13, f4mul(G1, S2)); ACC(14, f4mul(G1, S3));
    ACC(15, f4mul(G2, S0)); ACC(16, f4mul(G2, S1));
    ACC(17, f4mul(G2, S2)); ACC(18, f4mul(G2, S3));
    ACC(19, f4mul(G0, G0)); ACC(20, f4mul(G0, G1)); ACC(21, f4mul(G0, G2));
    ACC(22, f4mul(G1, G1)); ACC(23, f4mul(G1, G2)); ACC(24, f4mul(G2, G2));
#undef ACC
  };

  // horizontal box of one vertically-boxed channel (by value, SROA-safe)
  auto hbox4 = [&](float4 sv) -> float4 {
    const float s1 = sv.x + sv.y, s2 = s1 + sv.z, ts = s2 + sv.w;
    const float incl = wave_incl_scan(ts);
    const float base = incl - ts;
    const float P0 = base + sv.x, P1 = base + s1, P2 = base + s2, P3 = incl;
    const float PW = __shfl(P3, min(relmax >> 2, 63));
    const float h0 = __shfl(P0, lane + 5), h1 = __shfl(P1, lane + 5);
    const float h2 = __shfl(P2, lane + 5), h3 = __shfl(P3, lane + 5);
    const float l1 = __shfl(P0, lane + 1), l2 = __shfl(P1, lane + 1);
    const float l3 = __shfl(P2, lane + 1);
    const int r0 = 4 * lane + 12;
    float4 o;
    o.x = ((r0 + 8 <= relmax) ? h0 : PW) - ((E + r0 >= 9) ? P3 : 0.f);
    o.y = ((r0 + 9 <= relmax) ? h1 : PW) - ((E + r0 + 1 >= 9) ? l1 : 0.f);
    o.z = ((r0 + 10 <= relmax) ? h2 : PW) - ((E + r0 + 2 >= 9) ? l2 : 0.f);
    o.w = ((r0 + 11 <= relmax) ? h3 : PW) - ((E + r0 + 3 >= 9) ? l3 : 0.f);
    return o;
  };

  // init window for first row
  for (int yy = y0 - RAD; yy <= y0 + RAD; ++yy) row_acc(yy, true);

  for (int row = y0; row < y0 + RROWS; ++row) {
    const int ny = min(row + RAD, HH - 1) - max(row - RAD, 0) + 1;
    const float invny = 1.0f / (float)ny;
    float invN[4];
#pragma unroll
    for (int j = 0; j < 4; ++j) invN[j] = invny * nxinv[j];

    // guide means
    float mI[3][4];
#pragma unroll
    for (int k = 0; k < 3; ++k) {
      const float4 t = hbox4(s[k]);
      mI[k][0] = t.x * invN[0]; mI[k][1] = t.y * invN[1];
      mI[k][2] = t.z * invN[2]; mI[k][3] = t.w * invN[3];
    }
    // covariance of guide -> inverse (symmetric 3x3)
    float inv[6][4];
    {
      const float4 t19 = hbox4(s[19]), t20 = hbox4(s[20]), t21 = hbox4(s[21]);
      const float4 t22 = hbox4(s[22]), t23 = hbox4(s[23]), t24 = hbox4(s[24]);
      const float v19[4] = {t19.x, t19.y, t19.z, t19.w};
      const float v20[4] = {t20.x, t20.y, t20.z, t20.w};
      const float v21[4] = {t21.x, t21.y, t21.z, t21.w};
      const float v22[4] = {t22.x, t22.y, t22.z, t22.w};
      const float v23[4] = {t23.x, t23.y, t23.z, t23.w};
      const float v24[4] = {t24.x, t24.y, t24.z, t24.w};
#pragma unroll
      for (int j = 0; j < 4; ++j) {
        const float rr = v19[j] * invN[j] - mI[0][j] * mI[0][j] + EPSF;
        const float rg = v20[j] * invN[j] - mI[0][j] * mI[1][j];
        const float rb = v21[j] * invN[j] - mI[0][j] * mI[2][j];
        const float gg = v22[j] * invN[j] - mI[1][j] * mI[1][j] + EPSF;
        const float gb = v23[j] * invN[j] - mI[1][j] * mI[2][j];
        const float bb = v24[j] * invN[j] - mI[2][j] * mI[2][j] + EPSF;
        const float det = rr * gg * bb + 2.f * rg * gb * rb
                        - rb * gg * rb - rg * rg * bb - rr * gb * gb;
        const float idet = 1.0f / det;
        inv[0][j] = (gg * bb - gb * gb) * idet;
        inv[1][j] = (rb * gb - rg * bb) * idet;
        inv[2][j] = (rg * gb - rb * gg) * idet;
        inv[3][j] = (rr * bb - rb * rb) * idet;
        inv[4][j] = (rb * rg - rr * gb) * idet;
        inv[5][j] = (rr * gg - rg * rg) * idet;
      }
    }

    const size_t obase = (size_t)row * WW + F + 4 * lane;
    // phase-B hbox over a/b from registers -> store one plane
    auto phaseB = [&](float4 vv, int plane) {
      const float s1 = vv.x + vv.y, s2 = s1 + vv.z, ts = s2 + vv.w;
      const float incl = wave_incl_scan(ts);
      const float base = incl - ts;
      const float Q0 = base + vv.x, Q1 = base + s1, Q2 = base + s2, Q3 = incl;
      const float PW2 = __shfl(Q3, min(qmax >> 2, 63));
      const float h0 = __shfl(Q0, lane + 4), h1 = __shfl(Q1, lane + 4);
      const float h2 = __shfl(Q2, lane + 4), h3 = __shfl(Q3, lane + 4);
      const float lm1 = __shfl(Q3, lane - 1);
      const int qf0 = 8 + 4 * lane;
      float4 o;
      o.x = ((qf0 + 8 <= qmax) ? h0 : PW2) - ((qf0 >= 9) ? lm1 : 0.f);
      o.y = ((qf0 + 9 <= qmax) ? h1 : PW2) - Q0;  // qf0+1 >= 9 always
      o.z = ((qf0 + 10 <= qmax) ? h2 : PW2) - Q1;
      o.w = ((qf0 + 11 <= qmax) ? h3 : PW2) - Q2;
      if (stok) *(float4*)(wsb + (size_t)plane * HWSZ + obase) = o;
    };

    // per-src-channel: solve -> a0,a1,a2,b, then phase-B + store
#pragma unroll
    for (int cc = 0; cc < 4; ++cc) {
      const float4 tmp = hbox4(s[3 + cc]);
      const float4 tq0 = hbox4(s[7 + cc]);
      const float4 tq1 = hbox4(s[11 + cc]);
      const float4 tq2 = hbox4(s[15 + cc]);
      const float mp[4] = {tmp.x, tmp.y, tmp.z, tmp.w};
      const float q0[4] = {tq0.x, tq0.y, tq0.z, tq0.w};
      const float q1[4] = {tq1.x, tq1.y, tq1.z, tq1.w};
      const float q2[4] = {tq2.x, tq2.y, tq2.z, tq2.w};
      float4 a0v, a1v, a2v, bv;
      float* pa0 = &a0v.x; float* pa1 = &a1v.x;
      float* pa2 = &a2v.x; float* pbv = &bv.x;
#pragma unroll
      for (int j = 0; j < 4; ++j) {
        const float m = mp[j] * invN[j];
        const float c0v = q0[j] * invN[j] - mI[0][j] * m;
        const float c1v = q1[j] * invN[j] - mI[1][j] * m;
        const float c2v = q2[j] * invN[j] - mI[2][j] * m;
        const float a0 = c0v * inv[0][j] + c1v * inv[1][j] + c2v * inv[2][j];
        const float a1 = c0v * inv[1][j] + c1v * inv[3][j] + c2v * inv[4][j];
        const float a2 = c0v * inv[2][j] + c1v * inv[4][j] + c2v * inv[5][j];
        const float b_ = m - (a0 * mI[0][j] + a1 * mI[1][j] + a2 * mI[2][j]);
        pa0[j] = abok ? a0 : 0.f;
        pa1[j] = abok ? a1 : 0.f;
        pa2[j] = abok ? a2 : 0.f;
        pbv[j] = abok ? b_ : 0.f;
      }
      phaseB(a0v, cc);
      phaseB(a1v, 4 + cc);
      phaseB(a2v, 8 + cc);
      phaseB(bv, 12 + cc);
    }

    // slide window: +row(row+9), -row(row-8)
    row_acc(row + RAD + 1, true);
    row_acc(row - RAD, false);
  }
}

// ---------------- K_B: vertical box of boxed a/b + combine with guide -> q
// 256-thread blocks, thread-per-column, V3R-row sliding window.
__global__ __launch_bounds__(256) void k_vbox_comb(const float* __restrict__ ws_,
                                                   const float* __restrict__ g,
                                                   float* __restrict__ out, int b0) {
  const int col = blockIdx.x * 256 + threadIdx.x;
  const int y0 = blockIdx.y * V3R;
  const int b = b0 + blockIdx.z;
  const float* wsb = ws_ + (size_t)blockIdx.z * NPLB * HWSZ;
  const float* gp0 = g + (size_t)(b * 3 + 0) * HWSZ;
  const float* gp1 = g + (size_t)(b * 3 + 1) * HWSZ;
  const float* gp2 = g + (size_t)(b * 3 + 2) * HWSZ;
  float* op0 = out + (size_t)(b * 4 + 0) * HWSZ;
  float* op1 = out + (size_t)(b * 4 + 1) * HWSZ;
  float* op2 = out + (size_t)(b * 4 + 2) * HWSZ;
  float* op3 = out + (size_t)(b * 4 + 3) * HWSZ;

  float acc[16];
#pragma unroll
  for (int i = 0; i < 16; ++i) acc[i] = 0.f;

  auto row_op = [&](int y, bool add) {
    const int off = y * WW + col;
#pragma unroll
    for (int i = 0; i < 16; ++i) {
      const float v = wsb[(size_t)i * HWSZ + off];
      acc[i] = add ? (acc[i] + v) : (acc[i] - v);
    }
  };

  for (int yy = y0 - RAD; yy <= y0 + RAD; ++yy)
    if (yy >= 0 && yy < HH) row_op(yy, true);

  const int nx = min(col + RAD, WW - 1) - max(col - RAD, 0) + 1;
  const float invnx = 1.0f / (float)nx;

  for (int y = y0; y < y0 + V3R; ++y) {
    const int ny = min(y + RAD, HH - 1) - max(y - RAD, 0) + 1;
    const float invN = invnx / (float)ny;
    const size_t off = (size_t)y * WW + col;
    const float g0 = gp0[off], g1 = gp1[off], g2 = gp2[off];
    op0[off] = (acc[0] * g0 + acc[4] * g1 + acc[8]  * g2 + acc[12]) * invN;
    op1[off] = (acc[1] * g0 + acc[5] * g1 + acc[9]  * g2 + acc[13]) * invN;
    op2[off] = (acc[2] * g0 + acc[6] * g1 + acc[10] * g2 + acc[14]) * invN;
    op3[off] = (acc[3] * g0 + acc[7] * g1 + acc[11] * g2 + acc[15]) * invN;
    const int ye = y + RAD + 1;
    if (ye < HH) row_op(ye, true);
    const int yl = y - RAD;
    if (yl >= 0) row_op(yl, false);
  }
}

extern "C" void kernel_launch(void* const* d_in, const int* in_sizes, int n_in,
                              void* d_out, int out_size, void* d_ws, size_t ws_size,
                              hipStream_t stream) {
  const float* x = (const float*)d_in[0];   // (4,4,1024,1024) src p
  const float* g = (const float*)d_in[1];   // (4,3,1024,1024) guide
  float* out = (float*)d_out;
  float* ws = (float*)d_ws;
  const size_t perBatchBytes = (size_t)NPLB * HWSZ * sizeof(float);  // 64 MB
  int nb = (int)(ws_size / perBatchBytes);
  if (nb < 1) nb = 1;
  if (nb > 4) nb = 4;
  for (int b0 = 0; b0 < 4; b0 += nb) {
    const int nbc = (4 - b0 < nb) ? (4 - b0) : nb;
    dim3 gA((HH / RROWS) * NTL / 4, nbc);
    dim3 gB(WW / 256, HH / V3R, nbc);
    hipLaunchKernelGGL(k_stats_solve, gA, dim3(256), 0, stream, x, g, ws, b0);
    hipLaunchKernelGGL(k_vbox_comb, gB, dim3(256), 0, stream, ws, g, out, b0);
  }
}